// Round 2
// baseline (57.675 us; speedup 1.0000x reference)
//
#include <hip/hip_runtime.h>

#define NR 700
#define KK 250
#define HID 32

#if __has_builtin(__builtin_amdgcn_exp2f)
#define EXP2F(x) __builtin_amdgcn_exp2f(x)
#else
#define EXP2F(x) exp2f(x)
#endif

__device__ __forceinline__ float dot4(float4 a, float4 b) {
    return fmaf(a.x, b.x, fmaf(a.y, b.y, fmaf(a.z, b.z, a.w * b.w)));
}

__global__ __launch_bounds__(512, 6) void mlra_kernel(
    const float* __restrict__ power,
    const int*   __restrict__ ele_idx,
    const int*   __restrict__ azi_idx,
    const float* __restrict__ ele_emb,
    const float* __restrict__ azi_emb,
    const float* __restrict__ Wq,
    const float* __restrict__ bq,
    const float* __restrict__ Wk,
    const float* __restrict__ bk,
    const float* __restrict__ Wv,
    const float* __restrict__ bv,
    float* __restrict__ out)
{
    // h rows padded to 8 floats: [x, e0,e1,e2, a0,a1,a2, v]
    __shared__ float4 h4[KK][2];
    __shared__ float ps[4][256];   // partial sum-exp, per j-quarter
    __shared__ float po[4][256];   // partial sum-exp*v, per j-quarter
    __shared__ float Msh[7][7];
    __shared__ float wsh[7];
    __shared__ float wvsh[8];      // wv[0..6], bv in [7]

    float* hs = reinterpret_cast<float*>(h4);

    const int r   = blockIdx.x;
    const int tid = threadIdx.x;
    const int t   = tid & 127;   // row-pair id
    const int jq  = tid >> 7;    // j-quarter (0..3), wave-uniform

    // ---- load h rows (one row per thread) ----
    if (tid < KK) {
        int g = r * KK + tid;
        float x = power[g];
        int ei = ele_idx[g];
        int ai = azi_idx[g];
        float* hr = hs + tid * 8;
        hr[0] = x;
        hr[1] = ele_emb[ei * 3 + 0];
        hr[2] = ele_emb[ei * 3 + 1];
        hr[3] = ele_emb[ei * 3 + 2];
        hr[4] = azi_emb[ai * 3 + 0];
        hr[5] = azi_emb[ai * 3 + 1];
        hr[6] = azi_emb[ai * 3 + 2];
        hr[7] = 0.f;
    }

    const int  i0   = t;
    const int  i1v  = t + 128;
    const bool row1 = (i1v < KK);
    const int  i1   = row1 ? i1v : (KK - 1);

    // SCALE * log2(e) folded into the score constants so we can use raw exp2
    const float SC2 = 0.17677669529663687f * 1.4426950408889634f;

    float x0 = 0.f, x1 = 0.f;

    for (int l = 0; l < 2; ++l) {
        // ---- per-layer constants: M = SC2*Wq Wk^T (7x7), w = SC2*bq Wk^T, wv, bv ----
        const float* wq = Wq + l * 7 * HID;
        const float* wk = Wk + l * 7 * HID;
        if (tid < 49) {
            int c = tid / 7, cp = tid % 7;
            float s = 0.f;
            #pragma unroll 8
            for (int d = 0; d < HID; ++d) s = fmaf(wq[c * HID + d], wk[cp * HID + d], s);
            Msh[c][cp] = s * SC2;
        } else if (tid < 56) {
            int cp = tid - 49;
            float s = 0.f;
            #pragma unroll 8
            for (int d = 0; d < HID; ++d) s = fmaf(bq[l * HID + d], wk[cp * HID + d], s);
            wsh[cp] = s * SC2;
        } else if (tid < 63) {
            wvsh[tid - 56] = Wv[l * 7 + (tid - 56)];
        } else if (tid == 63) {
            wvsh[7] = bv[l];
        }
        __syncthreads();   // (a) constants ready; h stable

        // ---- per-row t-vectors (registers) and v (into h[i][7]) ----
        float4 t0a, t0b, t1a, t1b;
        {
            float hv0[7], hv1[7];
            float4 a0 = h4[i0][0], b0 = h4[i0][1];
            float4 a1 = h4[i1][0], b1 = h4[i1][1];
            hv0[0]=a0.x; hv0[1]=a0.y; hv0[2]=a0.z; hv0[3]=a0.w; hv0[4]=b0.x; hv0[5]=b0.y; hv0[6]=b0.z;
            hv1[0]=a1.x; hv1[1]=a1.y; hv1[2]=a1.z; hv1[3]=a1.w; hv1[4]=b1.x; hv1[5]=b1.y; hv1[6]=b1.z;
            float tt0[7], tt1[7];
            #pragma unroll
            for (int cp = 0; cp < 7; ++cp) {
                float s0 = wsh[cp], s1 = wsh[cp];
                #pragma unroll
                for (int c = 0; c < 7; ++c) {
                    float m = Msh[c][cp];
                    s0 = fmaf(hv0[c], m, s0);
                    s1 = fmaf(hv1[c], m, s1);
                }
                tt0[cp] = s0; tt1[cp] = s1;
            }
            t0a = make_float4(tt0[0], tt0[1], tt0[2], tt0[3]);
            t0b = make_float4(tt0[4], tt0[5], tt0[6], 0.f);   // .w=0 nullifies v slot
            t1a = make_float4(tt1[0], tt1[1], tt1[2], tt1[3]);
            t1b = make_float4(tt1[4], tt1[5], tt1[6], 0.f);
            if (jq == 0) {
                float v0 = wvsh[7], v1 = wvsh[7];
                #pragma unroll
                for (int c = 0; c < 7; ++c) {
                    v0 = fmaf(hv0[c], wvsh[c], v0);
                    v1 = fmaf(hv1[c], wvsh[c], v1);
                }
                hs[i0 * 8 + 7] = v0;
                if (row1) hs[i1 * 8 + 7] = v1;
            }
        }
        __syncthreads();   // (b) v visible

        // ---- main loop: this thread's j-quarter (strided, wave-uniform), 2 query rows ----
        float ss0 = 0.f, oo0 = 0.f, ss1 = 0.f, oo1 = 0.f;
        #pragma unroll 4
        for (int j = jq; j < KK; j += 4) {
            float4 ha = h4[j][0];   // broadcast LDS reads (jq uniform per wave)
            float4 hb = h4[j][1];
            float s0 = dot4(ha, t0a) + dot4(hb, t0b);
            float s1 = dot4(ha, t1a) + dot4(hb, t1b);
            float p0 = EXP2F(s0);
            float p1 = EXP2F(s1);
            ss0 += p0; oo0 = fmaf(p0, hb.w, oo0);
            ss1 += p1; oo1 = fmaf(p1, hb.w, oo1);
        }
        ps[jq][i0] = ss0; po[jq][i0] = oo0;
        if (row1) { ps[jq][i1] = ss1; po[jq][i1] = oo1; }
        __syncthreads();   // (c) partials ready

        // ---- combine quarters, finalize row outputs ----
        if (jq == 0) {
            float s0 = (ps[0][i0] + ps[1][i0]) + (ps[2][i0] + ps[3][i0]);
            float o0 = (po[0][i0] + po[1][i0]) + (po[2][i0] + po[3][i0]);
            x0 = o0 / s0;
            if (row1) {
                float s1 = (ps[0][i1] + ps[1][i1]) + (ps[2][i1] + ps[3][i1]);
                float o1 = (po[0][i1] + po[1][i1]) + (po[2][i1] + po[3][i1]);
                x1 = o1 / s1;
            }
            if (l == 0) {           // feed layer-1 input
                hs[i0 * 8 + 0] = x0;
                if (row1) hs[i1 * 8 + 0] = x1;
            }
        }
        // next layer's barrier (a) publishes the h[i][0] update
    }

    if (jq == 0) {
        out[r * KK + i0] = x0;
        if (row1) out[r * KK + i1] = x1;
    }
}

extern "C" void kernel_launch(void* const* d_in, const int* in_sizes, int n_in,
                              void* d_out, int out_size, void* d_ws, size_t ws_size,
                              hipStream_t stream) {
    const float* power   = (const float*)d_in[0];
    const int*   ele     = (const int*)d_in[1];
    const int*   azi     = (const int*)d_in[2];
    const float* ele_emb = (const float*)d_in[3];
    const float* azi_emb = (const float*)d_in[4];
    const float* Wq      = (const float*)d_in[5];
    const float* bq      = (const float*)d_in[6];
    const float* Wk      = (const float*)d_in[7];
    const float* bk      = (const float*)d_in[8];
    const float* Wv      = (const float*)d_in[9];
    const float* bv      = (const float*)d_in[10];
    float* outp = (float*)d_out;

    hipLaunchKernelGGL(mlra_kernel, dim3(NR), dim3(512), 0, stream,
                       power, ele, azi, ele_emb, azi_emb, Wq, bq, Wk, bk, Wv, bv, outp);
}

// Round 3
// 38.360 us; speedup vs baseline: 1.5035x; 1.5035x over previous
//
#include <hip/hip_runtime.h>

#define NR 700
#define KK 250
#define HID 32

#if __has_builtin(__builtin_amdgcn_exp2f)
#define EXP2F(x) __builtin_amdgcn_exp2f(x)
#else
#define EXP2F(x) exp2f(x)
#endif

__device__ __forceinline__ float dot4(float4 a, float4 b) {
    return fmaf(a.x, b.x, fmaf(a.y, b.y, fmaf(a.z, b.z, a.w * b.w)));
}

// 512 threads = 8 waves/block; min 4 waves/EU -> VGPR cap 128 (no spill).
__global__ __launch_bounds__(512, 4) void mlra_kernel(
    const float* __restrict__ power,
    const int*   __restrict__ ele_idx,
    const int*   __restrict__ azi_idx,
    const float* __restrict__ ele_emb,
    const float* __restrict__ azi_emb,
    const float* __restrict__ Wq,
    const float* __restrict__ bq,
    const float* __restrict__ Wk,
    const float* __restrict__ bk,
    const float* __restrict__ Wv,
    const float* __restrict__ bv,
    float* __restrict__ out)
{
    // h rows padded to 8 floats: [x, e0,e1,e2, a0,a1,a2, v]
    __shared__ float4 h4[KK][2];
    __shared__ float ps[4][256];   // partial sum-exp, per j-quarter
    __shared__ float po[4][256];   // partial sum-exp*v, per j-quarter
    __shared__ float Msh[7][7];
    __shared__ float wsh[7];
    __shared__ float wvsh[8];      // wv[0..6], bv in [7]

    float* hs = reinterpret_cast<float*>(h4);

    const int r   = blockIdx.x;
    const int tid = threadIdx.x;
    const int t   = tid & 127;   // row-pair id
    const int jq  = tid >> 7;    // j-quarter (0..3), wave-uniform

    // ---- load h rows (one row per thread) ----
    if (tid < KK) {
        int g = r * KK + tid;
        float x = power[g];
        int ei = ele_idx[g];
        int ai = azi_idx[g];
        float* hr = hs + tid * 8;
        hr[0] = x;
        hr[1] = ele_emb[ei * 3 + 0];
        hr[2] = ele_emb[ei * 3 + 1];
        hr[3] = ele_emb[ei * 3 + 2];
        hr[4] = azi_emb[ai * 3 + 0];
        hr[5] = azi_emb[ai * 3 + 1];
        hr[6] = azi_emb[ai * 3 + 2];
        hr[7] = 0.f;
    }

    const int  i0   = t;
    const int  i1v  = t + 128;
    const bool row1 = (i1v < KK);
    const int  i1   = row1 ? i1v : (KK - 1);

    // SCALE * log2(e) folded into the score constants so we can use raw exp2
    const float SC2 = 0.17677669529663687f * 1.4426950408889634f;

    float x0 = 0.f, x1 = 0.f;

    for (int l = 0; l < 2; ++l) {
        // ---- per-layer constants: M = SC2*Wq Wk^T (7x7), w = SC2*bq Wk^T, wv, bv ----
        const float* wq = Wq + l * 7 * HID;
        const float* wk = Wk + l * 7 * HID;
        if (tid < 49) {
            int c = tid / 7, cp = tid % 7;
            float s = 0.f;
            #pragma unroll 8
            for (int d = 0; d < HID; ++d) s = fmaf(wq[c * HID + d], wk[cp * HID + d], s);
            Msh[c][cp] = s * SC2;
        } else if (tid < 56) {
            int cp = tid - 49;
            float s = 0.f;
            #pragma unroll 8
            for (int d = 0; d < HID; ++d) s = fmaf(bq[l * HID + d], wk[cp * HID + d], s);
            wsh[cp] = s * SC2;
        } else if (tid < 63) {
            wvsh[tid - 56] = Wv[l * 7 + (tid - 56)];
        } else if (tid == 63) {
            wvsh[7] = bv[l];
        }
        __syncthreads();   // (a) constants ready; h stable

        // ---- per-row t-vectors (registers) and v (into h[i][7]) ----
        float4 t0a, t1a;
        float t0b0, t0b1, t0b2, t1b0, t1b1, t1b2;
        {
            float hv0[7], hv1[7];
            float4 a0 = h4[i0][0], b0 = h4[i0][1];
            float4 a1 = h4[i1][0], b1 = h4[i1][1];
            hv0[0]=a0.x; hv0[1]=a0.y; hv0[2]=a0.z; hv0[3]=a0.w; hv0[4]=b0.x; hv0[5]=b0.y; hv0[6]=b0.z;
            hv1[0]=a1.x; hv1[1]=a1.y; hv1[2]=a1.z; hv1[3]=a1.w; hv1[4]=b1.x; hv1[5]=b1.y; hv1[6]=b1.z;
            float tt0[7], tt1[7];
            #pragma unroll
            for (int cp = 0; cp < 7; ++cp) {
                float s0 = wsh[cp], s1 = wsh[cp];
                #pragma unroll
                for (int c = 0; c < 7; ++c) {
                    float m = Msh[c][cp];
                    s0 = fmaf(hv0[c], m, s0);
                    s1 = fmaf(hv1[c], m, s1);
                }
                tt0[cp] = s0; tt1[cp] = s1;
            }
            t0a = make_float4(tt0[0], tt0[1], tt0[2], tt0[3]);
            t0b0 = tt0[4]; t0b1 = tt0[5]; t0b2 = tt0[6];
            t1a = make_float4(tt1[0], tt1[1], tt1[2], tt1[3]);
            t1b0 = tt1[4]; t1b1 = tt1[5]; t1b2 = tt1[6];
            if (jq == 0) {
                float v0 = wvsh[7], v1 = wvsh[7];
                #pragma unroll
                for (int c = 0; c < 7; ++c) {
                    v0 = fmaf(hv0[c], wvsh[c], v0);
                    v1 = fmaf(hv1[c], wvsh[c], v1);
                }
                hs[i0 * 8 + 7] = v0;
                if (row1) hs[i1 * 8 + 7] = v1;
            }
        }
        __syncthreads();   // (b) v visible

        // ---- main loop: this thread's j-quarter (strided, wave-uniform), 2 query rows ----
        float ss0 = 0.f, oo0 = 0.f, ss1 = 0.f, oo1 = 0.f;
        #pragma unroll 5
        for (int j = jq; j < KK; j += 4) {
            float4 ha = h4[j][0];   // broadcast LDS reads (jq uniform per wave)
            float4 hb = h4[j][1];
            float s0 = fmaf(hb.z, t0b2, fmaf(hb.y, t0b1, fmaf(hb.x, t0b0, dot4(ha, t0a))));
            float s1 = fmaf(hb.z, t1b2, fmaf(hb.y, t1b1, fmaf(hb.x, t1b0, dot4(ha, t1a))));
            float p0 = EXP2F(s0);
            float p1 = EXP2F(s1);
            ss0 += p0; oo0 = fmaf(p0, hb.w, oo0);
            ss1 += p1; oo1 = fmaf(p1, hb.w, oo1);
        }
        ps[jq][i0] = ss0; po[jq][i0] = oo0;
        if (row1) { ps[jq][i1] = ss1; po[jq][i1] = oo1; }
        __syncthreads();   // (c) partials ready

        // ---- combine quarters, finalize row outputs ----
        if (jq == 0) {
            float s0 = (ps[0][i0] + ps[1][i0]) + (ps[2][i0] + ps[3][i0]);
            float o0 = (po[0][i0] + po[1][i0]) + (po[2][i0] + po[3][i0]);
            x0 = o0 / s0;
            if (row1) {
                float s1 = (ps[0][i1] + ps[1][i1]) + (ps[2][i1] + ps[3][i1]);
                float o1 = (po[0][i1] + po[1][i1]) + (po[2][i1] + po[3][i1]);
                x1 = o1 / s1;
            }
            if (l == 0) {           // feed layer-1 input
                hs[i0 * 8 + 0] = x0;
                if (row1) hs[i1 * 8 + 0] = x1;
            }
        }
        // next layer's barrier (a) publishes the h[i][0] update
    }

    if (jq == 0) {
        out[r * KK + i0] = x0;
        if (row1) out[r * KK + i1] = x1;
    }
}

extern "C" void kernel_launch(void* const* d_in, const int* in_sizes, int n_in,
                              void* d_out, int out_size, void* d_ws, size_t ws_size,
                              hipStream_t stream) {
    const float* power   = (const float*)d_in[0];
    const int*   ele     = (const int*)d_in[1];
    const int*   azi     = (const int*)d_in[2];
    const float* ele_emb = (const float*)d_in[3];
    const float* azi_emb = (const float*)d_in[4];
    const float* Wq      = (const float*)d_in[5];
    const float* bq      = (const float*)d_in[6];
    const float* Wk      = (const float*)d_in[7];
    const float* bk      = (const float*)d_in[8];
    const float* Wv      = (const float*)d_in[9];
    const float* bv      = (const float*)d_in[10];
    float* outp = (float*)d_out;

    hipLaunchKernelGGL(mlra_kernel, dim3(NR), dim3(512), 0, stream,
                       power, ele, azi, ele_emb, azi_emb, Wq, bq, Wk, bk, Wv, bv, outp);
}